// Round 4
// baseline (75.577 us; speedup 1.0000x reference)
//
#include <hip/hip_runtime.h>
#include <hip/hip_bf16.h>

// BallPredictorGNN: 2-layer GAT + MLP head; output depends ONLY on node N-1.
// S1 slots = [ball] ++ e0 (per-EDGE, dups allowed -> no dedup structures).
// S2 rows = one per (slot, in-edge) + selfloops. No fences, no completion
// counters: the whole layer-2 stage runs in ONE workgroup out of LDS.

#define NEG_SLOPE 0.2f
constexpr int F_IN   = 128;
constexpr int CH     = 64;
constexpr int D1     = 256;  // 4 heads * 64 ch
constexpr int SLOTS  = 64;   // max S1 slots = ne+1 (ne~32 expected)
constexpr int MAXDEG = 64;   // per-slot in-degree cap (~33 expected)
constexpr int CAPE0  = 256;  // e0 storage cap
constexpr int CAP2   = 4096; // S2 row cap (~1120 expected)
constexpr int ROWS3  = 8;    // S2 rows per k3 block

struct Ws {
    int* meta;     // [1]=rows2 [2]=ne
    int* e0;       // [CAPE0] src node of each ball in-edge
    int* deg;      // [SLOTS]
    int* dstrow;   // [SLOTS] S2 row holding slot's own h1
    int* nbr;      // [SLOTS*MAXDEG] S2 row indices
    int* list2;    // [CAP2] node id per S2 row
    float* H1c;    // [CAP2*D1]
    float* as1;    // [CAP2*4]
    float* ad1;    // [CAP2*4]
};

__device__ inline float wsum64(float v) {
    for (int o = 32; o > 0; o >>= 1) v += __shfl_xor(v, o, 64);
    return v;
}
__device__ inline float wmax64(float v) {
    for (int o = 32; o > 0; o >>= 1) v = fmaxf(v, __shfl_xor(v, o, 64));
    return v;
}

__global__ void kClear(Ws w) {
    int i = threadIdx.x;
    if (i < 16) w.meta[i] = 0;
    if (i < SLOTS) w.deg[i] = 0;
}

// scan edges for dst == ball -> e0 list (node ids, dups kept)
__global__ void k1_ball_edges(Ws w, const int* __restrict__ src,
                              const int* __restrict__ dst, int E, int ball) {
    int t = blockIdx.x * blockDim.x + threadIdx.x;
    int e0 = t * 4;
    if (e0 >= E) return;
    int4 dv = *(const int4*)&dst[e0];
    int dd[4] = {dv.x, dv.y, dv.z, dv.w};
#pragma unroll
    for (int k = 0; k < 4; k++) {
        int e = e0 + k;
        if (e < E && dd[k] == ball) {
            int p = atomicAdd(&w.meta[2], 1);
            if (p < CAPE0) w.e0[p] = src[e];
        }
    }
}

// prologue: per-slot selfloop S2 row + dstrow. main: scan edges, match dst
// against LDS slot list (all matches -> dup slots each get the edge).
__global__ __launch_bounds__(256) void k2_l1_edges(Ws w, const int* __restrict__ src,
                                                   const int* __restrict__ dst,
                                                   int E, int ball) {
    __shared__ int sList[SLOTS];
    int tid = threadIdx.x;
    int gt = blockIdx.x * blockDim.x + tid;
    int ne = min(w.meta[2], SLOTS - 1);
    int c1 = ne + 1;

    if (gt < c1) {  // slot gt: selfloop row
        int v = (gt == 0) ? ball : w.e0[gt - 1];
        int q = atomicAdd(&w.meta[1], 1);
        if (q < CAP2) {
            w.list2[q] = v;
            w.dstrow[gt] = q;
            int p = atomicAdd(&w.deg[gt], 1);
            if (p < MAXDEG) w.nbr[gt * MAXDEG + p] = q;
        }
    }
    for (int t = tid; t < c1; t += 256)
        sList[t] = (t == 0) ? ball : w.e0[t - 1];
    __syncthreads();

    int e0i = gt * 4;
    if (e0i >= E) return;
    int4 dv = *(const int4*)&dst[e0i];
    int dd[4] = {dv.x, dv.y, dv.z, dv.w};
#pragma unroll
    for (int k = 0; k < 4; k++) {
        int e = e0i + k;
        if (e >= E) break;
        int d = dd[k];
        for (int t = 0; t < c1; t++) {
            if (d == sList[t]) {
                int q = atomicAdd(&w.meta[1], 1);
                if (q < CAP2) {
                    w.list2[q] = src[e];
                    int p = atomicAdd(&w.deg[t], 1);
                    if (p < MAXDEG) w.nbr[t * MAXDEG + p] = q;
                }
            }
        }
    }
}

// h1 = x@W1 per S2 row (8 rows/block); alpha_s1/alpha_d1 per row
__global__ __launch_bounds__(256) void k3_h1(Ws w, const float* __restrict__ x,
                                             const float* __restrict__ W1,
                                             const float* __restrict__ a_s,
                                             const float* __restrict__ a_d) {
    int c2 = min(w.meta[1], CAP2);
    int base = blockIdx.x * ROWS3;
    if (base >= c2) return;
    __shared__ float xs[ROWS3][F_IN];
    int j = threadIdx.x;
    for (int t = j; t < ROWS3 * F_IN; t += 256) {
        int r = t >> 7, kk = t & 127;
        int idx = base + r;
        xs[r][kk] = (idx < c2) ? x[(size_t)w.list2[idx] * F_IN + kk] : 0.f;
    }
    __syncthreads();
    float acc[ROWS3];
#pragma unroll
    for (int r = 0; r < ROWS3; r++) acc[r] = 0.f;
#pragma unroll 4
    for (int k = 0; k < F_IN; k++) {
        float wv = W1[k * D1 + j];
#pragma unroll
        for (int r = 0; r < ROWS3; r++) acc[r] += xs[r][k] * wv;
    }
    int hh = j >> 6, cc = j & 63;
    float asv = a_s[hh * CH + cc], adv = a_d[hh * CH + cc];
#pragma unroll
    for (int r = 0; r < ROWS3; r++) {
        int idx = base + r;
        if (idx < c2) {
            w.H1c[idx * D1 + j] = acc[r];
            float vs = wsum64(acc[r] * asv);
            float vd = wsum64(acc[r] * adv);
            if (cc == 0) { w.as1[idx * 4 + hh] = vs; w.ad1[idx * 4 + hh] = vd; }
        }
    }
}

// ONE workgroup: per-slot layer-1 agg + W2 + alpha2 (16 waves, slots strided),
// then ball layer-2 softmax/agg + MLP head, all through LDS.
__global__ __launch_bounds__(1024) void k4_final(Ws w,
        const float* __restrict__ b1,  const float* __restrict__ W2,
        const float* __restrict__ a_s2, const float* __restrict__ a_d2,
        const float* __restrict__ b2,
        const float* __restrict__ fc1w, const float* __restrict__ fc1b,
        const float* __restrict__ fc2w, const float* __restrict__ fc2b,
        float* __restrict__ out) {
    __shared__ float sWt[16][MAXDEG][4];   // 16 KB per-wave edge weights
    __shared__ int   sRow[16][MAXDEG];     // 4 KB  per-wave S2 rows
    __shared__ float sO1[16][D1];          // 16 KB per-wave O1 buffer
    __shared__ float sH2[SLOTS][CH];       // 16 KB h2 per slot
    __shared__ float sAs2[SLOTS], sAd2[SLOTS];
    __shared__ float sWtC[SLOTS];
    __shared__ float sBall[CH];
    __shared__ float sZ[32];

    int tid  = threadIdx.x;
    int wv   = tid >> 6;
    int lane = tid & 63;
    int ne = min(w.meta[2], SLOTS - 1);
    int c1 = ne + 1;

    for (int s = wv; s < c1; s += 16) {
        int degS = min(w.deg[s], MAXDEG);
        int drow = w.dstrow[s];
        float4 ad4 = *(const float4*)&w.ad1[drow * 4];
        int r = -1;
        float4 e4 = make_float4(-1e30f, -1e30f, -1e30f, -1e30f);
        if (lane < degS) {
            r = w.nbr[s * MAXDEG + lane];
            float4 as4 = *(const float4*)&w.as1[r * 4];
            float ex = as4.x + ad4.x, ey = as4.y + ad4.y;
            float ez = as4.z + ad4.z, ew = as4.w + ad4.w;
            e4.x = ex > 0.f ? ex : NEG_SLOPE * ex;
            e4.y = ey > 0.f ? ey : NEG_SLOPE * ey;
            e4.z = ez > 0.f ? ez : NEG_SLOPE * ez;
            e4.w = ew > 0.f ? ew : NEG_SLOPE * ew;
        }
        float m0 = wmax64(e4.x), m1 = wmax64(e4.y);
        float m2 = wmax64(e4.z), m3 = wmax64(e4.w);
        float4 wt4 = make_float4(0.f, 0.f, 0.f, 0.f);
        if (lane < degS) {
            wt4.x = expf(e4.x - m0); wt4.y = expf(e4.y - m1);
            wt4.z = expf(e4.z - m2); wt4.w = expf(e4.w - m3);
        }
        float s0 = wsum64(wt4.x), s1 = wsum64(wt4.y);
        float s2 = wsum64(wt4.z), s3 = wsum64(wt4.w);
        *(float4*)&sWt[wv][lane][0] = wt4;
        sRow[wv][lane] = r;

        float a0 = 0.f, a1 = 0.f, a2 = 0.f, a3 = 0.f;
#pragma unroll 4
        for (int p = 0; p < degS; p++) {
            float4 wp = *(const float4*)&sWt[wv][p][0];
            const float* hp = w.H1c + (size_t)sRow[wv][p] * D1;
            a0 += wp.x * hp[lane];
            a1 += wp.y * hp[64 + lane];
            a2 += wp.z * hp[128 + lane];
            a3 += wp.w * hp[192 + lane];
        }
        float o0 = a0 / (s0 + 1e-16f) + b1[lane];
        float o1 = a1 / (s1 + 1e-16f) + b1[64 + lane];
        float o2 = a2 / (s2 + 1e-16f) + b1[128 + lane];
        float o3 = a3 / (s3 + 1e-16f) + b1[192 + lane];
        sO1[wv][lane]       = o0 > 0.f ? o0 : 0.f;
        sO1[wv][64 + lane]  = o1 > 0.f ? o1 : 0.f;
        sO1[wv][128 + lane] = o2 > 0.f ? o2 : 0.f;
        sO1[wv][192 + lane] = o3 > 0.f ? o3 : 0.f;

        // h2 = o1 @ W2 (lane = out channel)
        float h2 = 0.f;
#pragma unroll 8
        for (int k = 0; k < D1; k++) h2 += sO1[wv][k] * W2[k * CH + lane];
        sH2[s][lane] = h2;
        float vs = wsum64(h2 * a_s2[lane]);
        float vd = wsum64(h2 * a_d2[lane]);
        if (lane == 0) { sAs2[s] = vs; sAd2[s] = vd; }
    }
    __syncthreads();

    // ball layer-2 softmax over slots 0..ne (slot 0 = selfloop), lane = slot
    if (tid < 64) {
        float ad0 = sAd2[0];
        float e = -1e30f;
        if (tid <= ne) {
            e = sAs2[tid] + ad0;
            e = e > 0.f ? e : NEG_SLOPE * e;
        }
        float m = wmax64(e);
        float wt = (tid <= ne) ? expf(e - m) : 0.f;
        float ssum = wsum64(wt);
        sWtC[tid] = wt;
        float acc = 0.f;  // lane = channel
#pragma unroll 4
        for (int i = 0; i <= ne; i++) acc += sWtC[i] * sH2[i][tid];
        float bv = acc / (ssum + 1e-16f) + b2[tid];
        sBall[tid] = bv > 0.f ? bv : 0.f;
    }
    __syncthreads();
    if (tid < 32) {
        float a = fc1b[tid];
#pragma unroll 8
        for (int c = 0; c < CH; c++) a += sBall[c] * fc1w[c * 32 + tid];
        sZ[tid] = a > 0.f ? a : 0.f;
    }
    __syncthreads();
    if (tid < 2) {
        float a = fc2b[tid];
#pragma unroll 8
        for (int k = 0; k < 32; k++) a += sZ[k] * fc2w[k * 2 + tid];
        out[tid] = a;
    }
}

extern "C" void kernel_launch(void* const* d_in, const int* in_sizes, int n_in,
                              void* d_out, int out_size, void* d_ws, size_t ws_size,
                              hipStream_t stream) {
    const float* x    = (const float*)d_in[0];
    const int*   ei   = (const int*)d_in[1];
    const float* W1   = (const float*)d_in[2];
    const float* as1w = (const float*)d_in[3];
    const float* ad1w = (const float*)d_in[4];
    const float* b1   = (const float*)d_in[5];
    const float* W2   = (const float*)d_in[6];
    const float* as2w = (const float*)d_in[7];
    const float* ad2w = (const float*)d_in[8];
    const float* b2   = (const float*)d_in[9];
    const float* fc1w = (const float*)d_in[10];
    const float* fc1b = (const float*)d_in[11];
    const float* fc2w = (const float*)d_in[12];
    const float* fc2b = (const float*)d_in[13];

    int E = in_sizes[1] / 2;
    int N = in_sizes[0] / F_IN;
    int ball = N - 1;
    const int* srcA = ei;
    const int* dstA = ei + E;

    char* p = (char*)d_ws;
    auto carve = [&](size_t bytes) {
        void* r = (void*)p;
        p += (bytes + 255) & ~(size_t)255;
        return r;
    };
    Ws w;
    w.meta   = (int*)carve(16 * sizeof(int));
    w.e0     = (int*)carve(CAPE0 * sizeof(int));
    w.deg    = (int*)carve(SLOTS * sizeof(int));
    w.dstrow = (int*)carve(SLOTS * sizeof(int));
    w.nbr    = (int*)carve((size_t)SLOTS * MAXDEG * sizeof(int));
    w.list2  = (int*)carve(CAP2 * sizeof(int));
    w.H1c    = (float*)carve((size_t)CAP2 * D1 * sizeof(float));
    w.as1    = (float*)carve((size_t)CAP2 * 4 * sizeof(float));
    w.ad1    = (float*)carve((size_t)CAP2 * 4 * sizeof(float));

    int gE4 = (E / 4 + 255) / 256;
    kClear<<<1, 128, 0, stream>>>(w);
    k1_ball_edges<<<gE4, 256, 0, stream>>>(w, srcA, dstA, E, ball);
    k2_l1_edges<<<gE4, 256, 0, stream>>>(w, srcA, dstA, E, ball);
    k3_h1<<<CAP2 / ROWS3, 256, 0, stream>>>(w, x, W1, as1w, ad1w);
    k4_final<<<1, 1024, 0, stream>>>(w, b1, W2, as2w, ad2w, b2,
                                     fc1w, fc1b, fc2w, fc2b, (float*)d_out);
}

// Round 5
// 70.006 us; speedup vs baseline: 1.0796x; 1.0796x over previous
//
#include <hip/hip_runtime.h>
#include <hip/hip_bf16.h>

// BallPredictorGNN: 2-layer GAT + MLP head; output depends ONLY on node N-1.
// S1 slots = [ball] ++ e0 (per-EDGE, dups allowed). S2 rows = one per
// (slot, in-edge) + selfloops. Final stage in ONE workgroup, with the
// per-slot W2 GEMM algebraically eliminated:
//   as2[s] = O1r[s]·(W2@a_s2), ball_pre = (Σ α_s O1r[s]) @ W2.

#define NEG_SLOPE 0.2f
constexpr int F_IN   = 128;
constexpr int CH     = 64;
constexpr int D1     = 256;  // 4 heads * 64 ch
constexpr int SLOTS  = 64;   // max S1 slots = ne+1 (ne~32 expected)
constexpr int MAXDEG = 64;   // per-slot in-degree cap (~33 expected)
constexpr int CAPE0  = 256;  // e0 storage cap
constexpr int CAP2   = 4096; // S2 row cap (~1120 expected)
constexpr int ROWS3  = 8;    // S2 rows per k3 block

struct Ws {
    int* meta;     // [1]=rows2 [2]=ne
    int* e0;       // [CAPE0] src node of each ball in-edge
    int* deg;      // [SLOTS]
    int* dstrow;   // [SLOTS] S2 row holding slot's own h1
    int* nbr;      // [SLOTS*MAXDEG] S2 row indices
    int* list2;    // [CAP2] node id per S2 row
    float* H1c;    // [CAP2*D1]
    float* as1;    // [CAP2*4]
    float* ad1;    // [CAP2*4]
};

__device__ inline float wsum64(float v) {
    for (int o = 32; o > 0; o >>= 1) v += __shfl_xor(v, o, 64);
    return v;
}
__device__ inline float wmax64(float v) {
    for (int o = 32; o > 0; o >>= 1) v = fmaxf(v, __shfl_xor(v, o, 64));
    return v;
}

__global__ void kClear(Ws w) {
    int i = threadIdx.x;
    if (i < 16) w.meta[i] = 0;
    if (i < SLOTS) w.deg[i] = 0;
}

// scan edges for dst == ball -> e0 list (node ids, dups kept)
__global__ void k1_ball_edges(Ws w, const int* __restrict__ src,
                              const int* __restrict__ dst, int E, int ball) {
    int t = blockIdx.x * blockDim.x + threadIdx.x;
    int e0 = t * 4;
    if (e0 >= E) return;
    int4 dv = *(const int4*)&dst[e0];
    int dd[4] = {dv.x, dv.y, dv.z, dv.w};
#pragma unroll
    for (int k = 0; k < 4; k++) {
        int e = e0 + k;
        if (e < E && dd[k] == ball) {
            int p = atomicAdd(&w.meta[2], 1);
            if (p < CAPE0) w.e0[p] = src[e];
        }
    }
}

// prologue: per-slot selfloop S2 row + dstrow. main: scan edges, match dst
// against LDS slot list (all matches -> dup slots each get the edge).
__global__ __launch_bounds__(256) void k2_l1_edges(Ws w, const int* __restrict__ src,
                                                   const int* __restrict__ dst,
                                                   int E, int ball) {
    __shared__ int sList[SLOTS];
    int tid = threadIdx.x;
    int gt = blockIdx.x * blockDim.x + tid;
    int ne = min(w.meta[2], SLOTS - 1);
    int c1 = ne + 1;

    if (gt < c1) {  // slot gt: selfloop row
        int v = (gt == 0) ? ball : w.e0[gt - 1];
        int q = atomicAdd(&w.meta[1], 1);
        if (q < CAP2) {
            w.list2[q] = v;
            w.dstrow[gt] = q;
            int p = atomicAdd(&w.deg[gt], 1);
            if (p < MAXDEG) w.nbr[gt * MAXDEG + p] = q;
        }
    }
    for (int t = tid; t < c1; t += 256)
        sList[t] = (t == 0) ? ball : w.e0[t - 1];
    __syncthreads();

    int e0i = gt * 4;
    if (e0i >= E) return;
    int4 dv = *(const int4*)&dst[e0i];
    int dd[4] = {dv.x, dv.y, dv.z, dv.w};
#pragma unroll
    for (int k = 0; k < 4; k++) {
        int e = e0i + k;
        if (e >= E) break;
        int d = dd[k];
        for (int t = 0; t < c1; t++) {
            if (d == sList[t]) {
                int q = atomicAdd(&w.meta[1], 1);
                if (q < CAP2) {
                    w.list2[q] = src[e];
                    int p = atomicAdd(&w.deg[t], 1);
                    if (p < MAXDEG) w.nbr[t * MAXDEG + p] = q;
                }
            }
        }
    }
}

// h1 = x@W1 per S2 row (8 rows/block); alpha_s1/alpha_d1 per row
__global__ __launch_bounds__(256) void k3_h1(Ws w, const float* __restrict__ x,
                                             const float* __restrict__ W1,
                                             const float* __restrict__ a_s,
                                             const float* __restrict__ a_d) {
    int c2 = min(w.meta[1], CAP2);
    int base = blockIdx.x * ROWS3;
    if (base >= c2) return;
    __shared__ float xs[ROWS3][F_IN];
    int j = threadIdx.x;
    for (int t = j; t < ROWS3 * F_IN; t += 256) {
        int r = t >> 7, kk = t & 127;
        int idx = base + r;
        xs[r][kk] = (idx < c2) ? x[(size_t)w.list2[idx] * F_IN + kk] : 0.f;
    }
    __syncthreads();
    float acc[ROWS3];
#pragma unroll
    for (int r = 0; r < ROWS3; r++) acc[r] = 0.f;
#pragma unroll 4
    for (int k = 0; k < F_IN; k++) {
        float wv = W1[k * D1 + j];
#pragma unroll
        for (int r = 0; r < ROWS3; r++) acc[r] += xs[r][k] * wv;
    }
    int hh = j >> 6, cc = j & 63;
    float asv = a_s[hh * CH + cc], adv = a_d[hh * CH + cc];
#pragma unroll
    for (int r = 0; r < ROWS3; r++) {
        int idx = base + r;
        if (idx < c2) {
            w.H1c[idx * D1 + j] = acc[r];
            float vs = wsum64(acc[r] * asv);
            float vd = wsum64(acc[r] * adv);
            if (cc == 0) { w.as1[idx * 4 + hh] = vs; w.ad1[idx * 4 + hh] = vd; }
        }
    }
}

// ONE workgroup finale. Per-slot layer-1 agg (float4-coalesced), per-slot
// alpha2 scalars via precomputed u_s = W2@a_s2 (no per-slot GEMM), ball
// softmax, weighted O1 sum, ONE GEMV through W2, MLP head.
__global__ __launch_bounds__(1024) void k4_final(Ws w,
        const float* __restrict__ b1,  const float* __restrict__ W2,
        const float* __restrict__ a_s2, const float* __restrict__ a_d2,
        const float* __restrict__ b2,
        const float* __restrict__ fc1w, const float* __restrict__ fc1b,
        const float* __restrict__ fc2w, const float* __restrict__ fc2b,
        float* __restrict__ out) {
    __shared__ float sU[2][D1];           // u_s, u_d
    __shared__ float sO1[SLOTS][D1];      // relu'd layer-1 outputs (64 KB)
    __shared__ float sWt[16][MAXDEG][4];  // per-wave edge weights
    __shared__ int   sRow[16][MAXDEG];
    __shared__ float sAs2[SLOTS];
    __shared__ float sAd0;
    __shared__ float sAlpha[SLOTS];
    __shared__ float sBallPre[D1];
    __shared__ float sPart[16][CH];
    __shared__ float sBall[CH];
    __shared__ float sZ[32];

    int tid  = threadIdx.x;
    int wv   = tid >> 6;
    int lane = tid & 63;
    int ne = min(w.meta[2], SLOTS - 1);
    int c1 = ne + 1;

    // phase 0: u_s = W2 @ a_s2, u_d = W2 @ a_d2 (wave wv owns 16 k-rows)
    {
        float as2l = a_s2[lane], ad2l = a_d2[lane];
#pragma unroll
        for (int kk = 0; kk < 16; kk++) {
            int k = wv * 16 + kk;
            float w2v = W2[k * CH + lane];
            float us = wsum64(w2v * as2l);
            float ud = wsum64(w2v * ad2l);
            if (lane == 0) { sU[0][k] = us; sU[1][k] = ud; }
        }
    }
    __syncthreads();

    // phase 1: slots strided over waves
    for (int s = wv; s < c1; s += 16) {
        int degS = min(w.deg[s], MAXDEG);
        int drow = w.dstrow[s];
        float4 ad4 = *(const float4*)&w.ad1[drow * 4];
        int r = 0;
        float4 e4 = make_float4(-1e30f, -1e30f, -1e30f, -1e30f);
        if (lane < degS) {
            r = w.nbr[s * MAXDEG + lane];
            float4 as4 = *(const float4*)&w.as1[r * 4];
            float ex = as4.x + ad4.x, ey = as4.y + ad4.y;
            float ez = as4.z + ad4.z, ew = as4.w + ad4.w;
            e4.x = ex > 0.f ? ex : NEG_SLOPE * ex;
            e4.y = ey > 0.f ? ey : NEG_SLOPE * ey;
            e4.z = ez > 0.f ? ez : NEG_SLOPE * ez;
            e4.w = ew > 0.f ? ew : NEG_SLOPE * ew;
        }
        float m0 = wmax64(e4.x), m1 = wmax64(e4.y);
        float m2 = wmax64(e4.z), m3 = wmax64(e4.w);
        float4 wt4 = make_float4(0.f, 0.f, 0.f, 0.f);
        if (lane < degS) {
            wt4.x = expf(e4.x - m0); wt4.y = expf(e4.y - m1);
            wt4.z = expf(e4.z - m2); wt4.w = expf(e4.w - m3);
        }
        float s0 = wsum64(wt4.x), s1 = wsum64(wt4.y);
        float s2 = wsum64(wt4.z), s3 = wsum64(wt4.w);
        *(float4*)&sWt[wv][lane][0] = wt4;
        sRow[wv][lane] = r;

        // agg: lane covers channels [4*lane,4*lane+4), head = lane>>4
        int h = lane >> 4;
        float den = (h == 0) ? s0 : (h == 1) ? s1 : (h == 2) ? s2 : s3;
        float4 b14 = *(const float4*)&b1[4 * lane];
        float ax = 0.f, ay = 0.f, az = 0.f, aw = 0.f;
#pragma unroll 4
        for (int p = 0; p < degS; p++) {
            float wt = sWt[wv][p][h];
            float4 hp = *(const float4*)&w.H1c[(size_t)sRow[wv][p] * D1 + 4 * lane];
            ax += wt * hp.x; ay += wt * hp.y;
            az += wt * hp.z; aw += wt * hp.w;
        }
        float inv = 1.f / (den + 1e-16f);
        float4 o;
        o.x = ax * inv + b14.x; o.y = ay * inv + b14.y;
        o.z = az * inv + b14.z; o.w = aw * inv + b14.w;
        o.x = o.x > 0.f ? o.x : 0.f; o.y = o.y > 0.f ? o.y : 0.f;
        o.z = o.z > 0.f ? o.z : 0.f; o.w = o.w > 0.f ? o.w : 0.f;
        *(float4*)&sO1[s][4 * lane] = o;

        float4 us4 = *(const float4*)&sU[0][4 * lane];
        float ds = wsum64(o.x * us4.x + o.y * us4.y + o.z * us4.z + o.w * us4.w);
        if (lane == 0) sAs2[s] = ds;
        if (s == 0) {
            float4 ud4 = *(const float4*)&sU[1][4 * lane];
            float dd = wsum64(o.x * ud4.x + o.y * ud4.y + o.z * ud4.z + o.w * ud4.w);
            if (lane == 0) sAd0 = dd;
        }
    }
    __syncthreads();

    // ball layer-2 softmax over slots (slot 0 = selfloop), lane = slot
    if (tid < 64) {
        float e = -1e30f;
        if (tid < c1) {
            e = sAs2[tid] + sAd0;
            e = e > 0.f ? e : NEG_SLOPE * e;
        }
        float m = wmax64(e);
        float wt = (tid < c1) ? expf(e - m) : 0.f;
        float ssum = wsum64(wt);
        if (tid < c1) sAlpha[tid] = wt / (ssum + 1e-16f);
    }
    __syncthreads();

    // ball_pre = sum_s alpha_s * O1r[s]   (256 channels, waves 0-3)
    if (tid < D1) {
        float acc = 0.f;
        for (int s = 0; s < c1; s++) acc += sAlpha[s] * sO1[s][tid];
        sBallPre[tid] = acc;
    }
    __syncthreads();

    // one GEMV: ball_v = relu(ball_pre @ W2 + b2); wave wv owns 16 k-rows
    {
        float acc = 0.f;
#pragma unroll
        for (int kk = 0; kk < 16; kk++) {
            int k = wv * 16 + kk;
            acc += sBallPre[k] * W2[k * CH + lane];
        }
        sPart[wv][lane] = acc;
    }
    __syncthreads();
    if (tid < 64) {
        float bv = b2[lane];
#pragma unroll
        for (int ww = 0; ww < 16; ww++) bv += sPart[ww][lane];
        sBall[lane] = bv > 0.f ? bv : 0.f;
    }
    __syncthreads();
    if (tid < 32) {
        float a = fc1b[tid];
#pragma unroll 8
        for (int c = 0; c < CH; c++) a += sBall[c] * fc1w[c * 32 + tid];
        sZ[tid] = a > 0.f ? a : 0.f;
    }
    __syncthreads();
    if (tid < 2) {
        float a = fc2b[tid];
#pragma unroll 8
        for (int k = 0; k < 32; k++) a += sZ[k] * fc2w[k * 2 + tid];
        out[tid] = a;
    }
}

extern "C" void kernel_launch(void* const* d_in, const int* in_sizes, int n_in,
                              void* d_out, int out_size, void* d_ws, size_t ws_size,
                              hipStream_t stream) {
    const float* x    = (const float*)d_in[0];
    const int*   ei   = (const int*)d_in[1];
    const float* W1   = (const float*)d_in[2];
    const float* as1w = (const float*)d_in[3];
    const float* ad1w = (const float*)d_in[4];
    const float* b1   = (const float*)d_in[5];
    const float* W2   = (const float*)d_in[6];
    const float* as2w = (const float*)d_in[7];
    const float* ad2w = (const float*)d_in[8];
    const float* b2   = (const float*)d_in[9];
    const float* fc1w = (const float*)d_in[10];
    const float* fc1b = (const float*)d_in[11];
    const float* fc2w = (const float*)d_in[12];
    const float* fc2b = (const float*)d_in[13];

    int E = in_sizes[1] / 2;
    int N = in_sizes[0] / F_IN;
    int ball = N - 1;
    const int* srcA = ei;
    const int* dstA = ei + E;

    char* p = (char*)d_ws;
    auto carve = [&](size_t bytes) {
        void* r = (void*)p;
        p += (bytes + 255) & ~(size_t)255;
        return r;
    };
    Ws w;
    w.meta   = (int*)carve(16 * sizeof(int));
    w.e0     = (int*)carve(CAPE0 * sizeof(int));
    w.deg    = (int*)carve(SLOTS * sizeof(int));
    w.dstrow = (int*)carve(SLOTS * sizeof(int));
    w.nbr    = (int*)carve((size_t)SLOTS * MAXDEG * sizeof(int));
    w.list2  = (int*)carve(CAP2 * sizeof(int));
    w.H1c    = (float*)carve((size_t)CAP2 * D1 * sizeof(float));
    w.as1    = (float*)carve((size_t)CAP2 * 4 * sizeof(float));
    w.ad1    = (float*)carve((size_t)CAP2 * 4 * sizeof(float));

    int gE4 = (E / 4 + 255) / 256;
    kClear<<<1, 128, 0, stream>>>(w);
    k1_ball_edges<<<gE4, 256, 0, stream>>>(w, srcA, dstA, E, ball);
    k2_l1_edges<<<gE4, 256, 0, stream>>>(w, srcA, dstA, E, ball);
    k3_h1<<<CAP2 / ROWS3, 256, 0, stream>>>(w, x, W1, as1w, ad1w);
    k4_final<<<1, 1024, 0, stream>>>(w, b1, W2, as2w, ad2w, b2,
                                     fc1w, fc1b, fc2w, fc2b, (float*)d_out);
}

// Round 6
// 62.874 us; speedup vs baseline: 1.2020x; 1.1134x over previous
//
#include <hip/hip_runtime.h>
#include <hip/hip_bf16.h>

// BallPredictorGNN: 2-layer GAT + MLP head; output depends ONLY on node N-1.
// S1 slots = [ball] ++ e0 (per-EDGE, dups allowed). S2 rows = one per
// (slot, in-edge) + selfloops. Layer-1 aggregation parallelized ONE BLOCK
// PER SLOT (k4a) so the latency-bound gathers overlap chip-wide; tiny
// single-block tail (k4b) does the layer-2 ball softmax + MLP from bulk
// coalesced reads. Per-slot W2 GEMM algebraically eliminated:
//   as2[s] = O1r[s]·(W2@a_s2), ball_pre = (Σ α_s O1r[s]) @ W2.

#define NEG_SLOPE 0.2f
constexpr int F_IN   = 128;
constexpr int CH     = 64;
constexpr int D1     = 256;  // 4 heads * 64 ch
constexpr int SLOTS  = 64;   // max S1 slots = ne+1 (ne~32 expected)
constexpr int MAXDEG = 64;   // per-slot in-degree cap (~33 expected)
constexpr int CAPE0  = 256;  // e0 storage cap
constexpr int CAP2   = 4096; // S2 row cap (~1120 expected)
constexpr int ROWS3  = 8;    // S2 rows per k3 block

struct Ws {
    int* meta;     // [1]=rows2 [2]=ne
    int* e0;       // [CAPE0] src node of each ball in-edge
    int* deg;      // [SLOTS]
    int* dstrow;   // [SLOTS] S2 row holding slot's own h1
    int* nbr;      // [SLOTS*MAXDEG] S2 row indices
    int* list2;    // [CAP2] node id per S2 row
    float* H1c;    // [CAP2*D1]
    float* as1;    // [CAP2*4]
    float* ad1;    // [CAP2*4]
    float* O1;     // [SLOTS*D1] relu'd layer-1 outputs per slot
};

__device__ inline float wsum64(float v) {
    for (int o = 32; o > 0; o >>= 1) v += __shfl_xor(v, o, 64);
    return v;
}
__device__ inline float wmax64(float v) {
    for (int o = 32; o > 0; o >>= 1) v = fmaxf(v, __shfl_xor(v, o, 64));
    return v;
}

__global__ void kClear(Ws w) {
    int i = threadIdx.x;
    if (i < 16) w.meta[i] = 0;
    if (i < SLOTS) w.deg[i] = 0;
}

// scan edges for dst == ball -> e0 list (node ids, dups kept)
__global__ void k1_ball_edges(Ws w, const int* __restrict__ src,
                              const int* __restrict__ dst, int E, int ball) {
    int t = blockIdx.x * blockDim.x + threadIdx.x;
    int e0 = t * 4;
    if (e0 >= E) return;
    int4 dv = *(const int4*)&dst[e0];
    int dd[4] = {dv.x, dv.y, dv.z, dv.w};
#pragma unroll
    for (int k = 0; k < 4; k++) {
        int e = e0 + k;
        if (e < E && dd[k] == ball) {
            int p = atomicAdd(&w.meta[2], 1);
            if (p < CAPE0) w.e0[p] = src[e];
        }
    }
}

// prologue: per-slot selfloop S2 row + dstrow. main: scan edges, match dst
// against LDS slot list (all matches -> dup slots each get the edge).
__global__ __launch_bounds__(256) void k2_l1_edges(Ws w, const int* __restrict__ src,
                                                   const int* __restrict__ dst,
                                                   int E, int ball) {
    __shared__ int sList[SLOTS];
    int tid = threadIdx.x;
    int gt = blockIdx.x * blockDim.x + tid;
    int ne = min(w.meta[2], SLOTS - 1);
    int c1 = ne + 1;

    if (gt < c1) {  // slot gt: selfloop row
        int v = (gt == 0) ? ball : w.e0[gt - 1];
        int q = atomicAdd(&w.meta[1], 1);
        if (q < CAP2) {
            w.list2[q] = v;
            w.dstrow[gt] = q;
            int p = atomicAdd(&w.deg[gt], 1);
            if (p < MAXDEG) w.nbr[gt * MAXDEG + p] = q;
        }
    }
    for (int t = tid; t < c1; t += 256)
        sList[t] = (t == 0) ? ball : w.e0[t - 1];
    __syncthreads();

    int e0i = gt * 4;
    if (e0i >= E) return;
    int4 dv = *(const int4*)&dst[e0i];
    int dd[4] = {dv.x, dv.y, dv.z, dv.w};
#pragma unroll
    for (int k = 0; k < 4; k++) {
        int e = e0i + k;
        if (e >= E) break;
        int d = dd[k];
        for (int t = 0; t < c1; t++) {
            if (d == sList[t]) {
                int q = atomicAdd(&w.meta[1], 1);
                if (q < CAP2) {
                    w.list2[q] = src[e];
                    int p = atomicAdd(&w.deg[t], 1);
                    if (p < MAXDEG) w.nbr[t * MAXDEG + p] = q;
                }
            }
        }
    }
}

// h1 = x@W1 per S2 row (8 rows/block); alpha_s1/alpha_d1 per row
__global__ __launch_bounds__(256) void k3_h1(Ws w, const float* __restrict__ x,
                                             const float* __restrict__ W1,
                                             const float* __restrict__ a_s,
                                             const float* __restrict__ a_d) {
    int c2 = min(w.meta[1], CAP2);
    int base = blockIdx.x * ROWS3;
    if (base >= c2) return;
    __shared__ float xs[ROWS3][F_IN];
    int j = threadIdx.x;
    for (int t = j; t < ROWS3 * F_IN; t += 256) {
        int r = t >> 7, kk = t & 127;
        int idx = base + r;
        xs[r][kk] = (idx < c2) ? x[(size_t)w.list2[idx] * F_IN + kk] : 0.f;
    }
    __syncthreads();
    float acc[ROWS3];
#pragma unroll
    for (int r = 0; r < ROWS3; r++) acc[r] = 0.f;
#pragma unroll 4
    for (int k = 0; k < F_IN; k++) {
        float wv = W1[k * D1 + j];
#pragma unroll
        for (int r = 0; r < ROWS3; r++) acc[r] += xs[r][k] * wv;
    }
    int hh = j >> 6, cc = j & 63;
    float asv = a_s[hh * CH + cc], adv = a_d[hh * CH + cc];
#pragma unroll
    for (int r = 0; r < ROWS3; r++) {
        int idx = base + r;
        if (idx < c2) {
            w.H1c[idx * D1 + j] = acc[r];
            float vs = wsum64(acc[r] * asv);
            float vd = wsum64(acc[r] * adv);
            if (cc == 0) { w.as1[idx * 4 + hh] = vs; w.ad1[idx * 4 + hh] = vd; }
        }
    }
}

// ONE BLOCK PER SLOT: layer-1 softmax (wave 0) + aggregation (256 threads,
// thread = channel -> fully coalesced 1KB H1c rows). Writes O1r[s].
__global__ __launch_bounds__(256) void k4a_slot_agg(Ws w, const float* __restrict__ b1) {
    int s = blockIdx.x;
    int ne = min(w.meta[2], SLOTS - 1);
    int c1 = ne + 1;
    if (s >= c1) return;

    __shared__ float sWt[MAXDEG][4];
    __shared__ int   sRow[MAXDEG];
    __shared__ float sInv[4];

    int tid = threadIdx.x;
    int degS = min(w.deg[s], MAXDEG);

    if (tid < 64) {
        int lane = tid;
        int drow = w.dstrow[s];
        float4 ad4 = *(const float4*)&w.ad1[drow * 4];
        int r = 0;
        float4 e4 = make_float4(-1e30f, -1e30f, -1e30f, -1e30f);
        if (lane < degS) {
            r = w.nbr[s * MAXDEG + lane];
            float4 as4 = *(const float4*)&w.as1[r * 4];
            float ex = as4.x + ad4.x, ey = as4.y + ad4.y;
            float ez = as4.z + ad4.z, ew = as4.w + ad4.w;
            e4.x = ex > 0.f ? ex : NEG_SLOPE * ex;
            e4.y = ey > 0.f ? ey : NEG_SLOPE * ey;
            e4.z = ez > 0.f ? ez : NEG_SLOPE * ez;
            e4.w = ew > 0.f ? ew : NEG_SLOPE * ew;
        }
        float m0 = wmax64(e4.x), m1 = wmax64(e4.y);
        float m2 = wmax64(e4.z), m3 = wmax64(e4.w);
        float4 wt4 = make_float4(0.f, 0.f, 0.f, 0.f);
        if (lane < degS) {
            wt4.x = expf(e4.x - m0); wt4.y = expf(e4.y - m1);
            wt4.z = expf(e4.z - m2); wt4.w = expf(e4.w - m3);
        }
        float s0 = wsum64(wt4.x), s1 = wsum64(wt4.y);
        float s2 = wsum64(wt4.z), s3 = wsum64(wt4.w);
        *(float4*)&sWt[lane][0] = wt4;
        sRow[lane] = r;
        if (lane == 0) {
            sInv[0] = 1.f / (s0 + 1e-16f); sInv[1] = 1.f / (s1 + 1e-16f);
            sInv[2] = 1.f / (s2 + 1e-16f); sInv[3] = 1.f / (s3 + 1e-16f);
        }
    }
    __syncthreads();

    int h = tid >> 6;  // wave-uniform -> sWt broadcast reads
    float acc = 0.f;
#pragma unroll 4
    for (int p = 0; p < degS; p++)
        acc += sWt[p][h] * w.H1c[(size_t)sRow[p] * D1 + tid];
    float o = acc * sInv[h] + b1[tid];
    w.O1[s * D1 + tid] = o > 0.f ? o : 0.f;
}

// ONE block tail: u_s/u_d GEMVs, as2 dots, ball softmax, weighted O1 sum,
// one W2 GEMV, MLP head. All reads bulk-coalesced (O1 33KB + W2 64KB).
__global__ __launch_bounds__(1024) void k4b_tail(Ws w,
        const float* __restrict__ W2,
        const float* __restrict__ a_s2, const float* __restrict__ a_d2,
        const float* __restrict__ b2,
        const float* __restrict__ fc1w, const float* __restrict__ fc1b,
        const float* __restrict__ fc2w, const float* __restrict__ fc2b,
        float* __restrict__ out) {
    __shared__ float sU[2][D1];
    __shared__ float sAs2[SLOTS];
    __shared__ float sAd0;
    __shared__ float sAlpha[SLOTS];
    __shared__ float sBallPre[D1];
    __shared__ float sPart[16][CH];
    __shared__ float sBall[CH];
    __shared__ float sZ[32];

    int tid  = threadIdx.x;
    int wv   = tid >> 6;
    int lane = tid & 63;
    int ne = min(w.meta[2], SLOTS - 1);
    int c1 = ne + 1;

    // u_s = W2 @ a_s2, u_d = W2 @ a_d2 (wave wv owns 16 k-rows)
    {
        float as2l = a_s2[lane], ad2l = a_d2[lane];
#pragma unroll
        for (int kk = 0; kk < 16; kk++) {
            int k = wv * 16 + kk;
            float w2v = W2[k * CH + lane];
            float us = wsum64(w2v * as2l);
            float ud = wsum64(w2v * ad2l);
            if (lane == 0) { sU[0][k] = us; sU[1][k] = ud; }
        }
    }
    __syncthreads();

    // as2[s] = O1r[s]·u_s (wave per slot, strided); slot 0 also ·u_d
    for (int s = wv; s < c1; s += 16) {
        float4 o4 = *(const float4*)&w.O1[s * D1 + 4 * lane];
        float4 us4 = *(const float4*)&sU[0][4 * lane];
        float ds = wsum64(o4.x * us4.x + o4.y * us4.y + o4.z * us4.z + o4.w * us4.w);
        if (lane == 0) sAs2[s] = ds;
        if (s == 0) {
            float4 ud4 = *(const float4*)&sU[1][4 * lane];
            float dd = wsum64(o4.x * ud4.x + o4.y * ud4.y + o4.z * ud4.z + o4.w * ud4.w);
            if (lane == 0) sAd0 = dd;
        }
    }
    __syncthreads();

    // ball layer-2 softmax over slots (slot 0 = selfloop), lane = slot
    if (tid < 64) {
        float e = -1e30f;
        if (tid < c1) {
            e = sAs2[tid] + sAd0;
            e = e > 0.f ? e : NEG_SLOPE * e;
        }
        float m = wmax64(e);
        float wt = (tid < c1) ? expf(e - m) : 0.f;
        float ssum = wsum64(wt);
        if (tid < c1) sAlpha[tid] = wt / (ssum + 1e-16f);
    }
    __syncthreads();

    // ball_pre = sum_s alpha_s * O1r[s]  (thread = channel, coalesced)
    if (tid < D1) {
        float acc = 0.f;
        for (int s = 0; s < c1; s++) acc += sAlpha[s] * w.O1[s * D1 + tid];
        sBallPre[tid] = acc;
    }
    __syncthreads();

    // ball_v = relu(ball_pre @ W2 + b2); wave wv owns 16 k-rows
    {
        float acc = 0.f;
#pragma unroll
        for (int kk = 0; kk < 16; kk++) {
            int k = wv * 16 + kk;
            acc += sBallPre[k] * W2[k * CH + lane];
        }
        sPart[wv][lane] = acc;
    }
    __syncthreads();
    if (tid < 64) {
        float bv = b2[lane];
#pragma unroll
        for (int ww = 0; ww < 16; ww++) bv += sPart[ww][lane];
        sBall[lane] = bv > 0.f ? bv : 0.f;
    }
    __syncthreads();
    if (tid < 32) {
        float a = fc1b[tid];
#pragma unroll 8
        for (int c = 0; c < CH; c++) a += sBall[c] * fc1w[c * 32 + tid];
        sZ[tid] = a > 0.f ? a : 0.f;
    }
    __syncthreads();
    if (tid < 2) {
        float a = fc2b[tid];
#pragma unroll 8
        for (int k = 0; k < 32; k++) a += sZ[k] * fc2w[k * 2 + tid];
        out[tid] = a;
    }
}

extern "C" void kernel_launch(void* const* d_in, const int* in_sizes, int n_in,
                              void* d_out, int out_size, void* d_ws, size_t ws_size,
                              hipStream_t stream) {
    const float* x    = (const float*)d_in[0];
    const int*   ei   = (const int*)d_in[1];
    const float* W1   = (const float*)d_in[2];
    const float* as1w = (const float*)d_in[3];
    const float* ad1w = (const float*)d_in[4];
    const float* b1   = (const float*)d_in[5];
    const float* W2   = (const float*)d_in[6];
    const float* as2w = (const float*)d_in[7];
    const float* ad2w = (const float*)d_in[8];
    const float* b2   = (const float*)d_in[9];
    const float* fc1w = (const float*)d_in[10];
    const float* fc1b = (const float*)d_in[11];
    const float* fc2w = (const float*)d_in[12];
    const float* fc2b = (const float*)d_in[13];

    int E = in_sizes[1] / 2;
    int N = in_sizes[0] / F_IN;
    int ball = N - 1;
    const int* srcA = ei;
    const int* dstA = ei + E;

    char* p = (char*)d_ws;
    auto carve = [&](size_t bytes) {
        void* r = (void*)p;
        p += (bytes + 255) & ~(size_t)255;
        return r;
    };
    Ws w;
    w.meta   = (int*)carve(16 * sizeof(int));
    w.e0     = (int*)carve(CAPE0 * sizeof(int));
    w.deg    = (int*)carve(SLOTS * sizeof(int));
    w.dstrow = (int*)carve(SLOTS * sizeof(int));
    w.nbr    = (int*)carve((size_t)SLOTS * MAXDEG * sizeof(int));
    w.list2  = (int*)carve(CAP2 * sizeof(int));
    w.H1c    = (float*)carve((size_t)CAP2 * D1 * sizeof(float));
    w.as1    = (float*)carve((size_t)CAP2 * 4 * sizeof(float));
    w.ad1    = (float*)carve((size_t)CAP2 * 4 * sizeof(float));
    w.O1     = (float*)carve((size_t)SLOTS * D1 * sizeof(float));

    int gE4 = (E / 4 + 255) / 256;
    kClear<<<1, 128, 0, stream>>>(w);
    k1_ball_edges<<<gE4, 256, 0, stream>>>(w, srcA, dstA, E, ball);
    k2_l1_edges<<<gE4, 256, 0, stream>>>(w, srcA, dstA, E, ball);
    k3_h1<<<CAP2 / ROWS3, 256, 0, stream>>>(w, x, W1, as1w, ad1w);
    k4a_slot_agg<<<SLOTS, 256, 0, stream>>>(w, b1);
    k4b_tail<<<1, 1024, 0, stream>>>(w, W2, as2w, ad2w, b2,
                                     fc1w, fc1b, fc2w, fc2b, (float*)d_out);
}